// Round 8
// baseline (271.503 us; speedup 1.0000x reference)
//
#include <hip/hip_runtime.h>
#include <hip/hip_bf16.h>
#include <cstdint>

#define B_ 8
#define C_ 512
#define T_ 1500
#define N_ (B_*T_)      // 12000 tokens
#define NPAD_ 12032
#define V_ 4096
#define K_ 100

typedef unsigned long long u64;
typedef __attribute__((ext_vector_type(8))) short short8;
typedef __attribute__((ext_vector_type(8))) unsigned short u16x8;
typedef __attribute__((ext_vector_type(4))) float f32x4;

__device__ __forceinline__ unsigned short f2bf(float x){
    __hip_bfloat16 h = __float2bfloat16(x);
    return __builtin_bit_cast(unsigned short, h);
}
__device__ __forceinline__ unsigned short f2h(float x){
    return __builtin_bit_cast(unsigned short, (_Float16)x);
}
__device__ __forceinline__ float h2f(unsigned short h){
    return (float)__builtin_bit_cast(_Float16, h);
}

__device__ __forceinline__ void gll16(const unsigned short* g, unsigned short* l){
    __builtin_amdgcn_global_load_lds(
        (const __attribute__((address_space(1))) void*)g,
        (__attribute__((address_space(3))) void*)l, 16, 0, 0);
}

// ---------------- codebook: fp32 -> bf16 + csq (fp32-exact) ----------------
__global__ __launch_bounds__(256) void cbconv_kernel(const float* __restrict__ CB,
                                                     unsigned short* __restrict__ CBh,
                                                     float* __restrict__ csq){
    int wv = threadIdx.x >> 6, lane = threadIdx.x & 63;
    int r = blockIdx.x * 4 + wv;
    const float4* p4 = (const float4*)(CB + (size_t)r * C_);
    ushort4* o4 = (ushort4*)(CBh + (size_t)r * C_);
    float s = 0.f;
    #pragma unroll
    for (int j = 0; j < 2; ++j){
        float4 v = p4[lane + j*64];
        s += v.x*v.x + v.y*v.y + v.z*v.z + v.w*v.w;
        ushort4 h; h.x = f2bf(v.x); h.y = f2bf(v.y); h.z = f2bf(v.z); h.w = f2bf(v.w);
        o4[lane + j*64] = h;
    }
    #pragma unroll
    for (int o = 32; o; o >>= 1) s += __shfl_down(s, o, 64);
    if (lane == 0) csq[r] = s;
}

// ---------------- student: (B,C,T) fp32 -> embT bf16 (N,C) + esq partials ----------------
__global__ __launch_bounds__(256) void transpose_conv_kernel(const float* __restrict__ S,
                                                             unsigned short* __restrict__ embT,
                                                             float* __restrict__ esq){
    __shared__ float tile[32][33];
    __shared__ float psum[8][33];
    int b  = blockIdx.z;
    int c0 = blockIdx.y * 32;
    int t0 = blockIdx.x * 32;
    int tx = threadIdx.x, ty = threadIdx.y; // 32 x 8
    #pragma unroll
    for (int r = 0; r < 4; ++r){
        int c = c0 + ty + r*8;
        int t = t0 + tx;
        tile[ty + r*8][tx] = (t < T_) ? S[((size_t)b*C_ + c)*T_ + t] : 0.f;
    }
    __syncthreads();
    float ps = 0.f;
    #pragma unroll
    for (int r = 0; r < 4; ++r){ float v = tile[ty + r*8][tx]; ps += v * v; }
    psum[ty][tx] = ps;
    #pragma unroll
    for (int r = 0; r < 4; ++r){
        int t = t0 + ty + r*8;
        int c = c0 + tx;
        if (t < T_) embT[((size_t)b*T_ + t)*C_ + c] = f2bf(tile[tx][ty + r*8]);
    }
    __syncthreads();
    if (ty == 0){
        int t = t0 + tx;
        if (t < T_){
            float s2 = 0.f;
            #pragma unroll
            for (int w = 0; w < 8; ++w) s2 += psum[w][tx];
            atomicAdd(&esq[b*T_ + t], s2);
        }
    }
}

// ---------------- bf16 MFMA GEMM -> fp16 dot matrix (r2-proven 2-barrier 128^2) ----------------
__global__ __launch_bounds__(256) void gemm_dot_kernel(
    const unsigned short* __restrict__ A, const unsigned short* __restrict__ Bm,
    unsigned short* __restrict__ doth, int row_lo, int row_hi)
{
    __shared__ unsigned short smem[128*136];   // 34816 B; staging (16 KB) aliased in front
    unsigned short* As = smem;                 // 128*32
    unsigned short* Bs = smem + 128*32;        // 128*32
    int tid = threadIdx.x, lane = tid & 63, wv = tid >> 6;
    int row0 = row_lo + blockIdx.x * 128;
    int col0 = blockIdx.y * 128;

    int sr = lane >> 2;
    int sk = (lane & 3) * 8;
    int ar0 = row0 + wv*32 + sr;       int ar1 = ar0 + 16;
    int ca0 = (ar0 < N_) ? ar0 : N_-1; int ca1 = (ar1 < N_) ? ar1 : N_-1;
    const unsigned short* Ap0 = A  + (size_t)ca0 * C_ + sk;
    const unsigned short* Ap1 = A  + (size_t)ca1 * C_ + sk;
    const unsigned short* Bp0 = Bm + (size_t)(col0 + wv*32 + sr) * C_ + sk;
    const unsigned short* Bp1 = Bp0 + (size_t)16 * C_;
    unsigned short* Ad0 = &As[(wv*32     ) * 32];
    unsigned short* Ad1 = &As[(wv*32 + 16) * 32];
    unsigned short* Bd0 = &Bs[(wv*32     ) * 32];
    unsigned short* Bd1 = &Bs[(wv*32 + 16) * 32];

    int wm = (wv >> 1) * 64, wn = (wv & 1) * 64;
    int fr = lane & 15;
    int fk = (lane >> 4) * 8;

    f32x4 acc[4][4];
    #pragma unroll
    for (int i = 0; i < 4; ++i)
        #pragma unroll
        for (int j = 0; j < 4; ++j) acc[i][j] = (f32x4){0.f, 0.f, 0.f, 0.f};

    for (int kt = 0; kt < C_/32; ++kt){
        int k0 = kt * 32;
        gll16(Ap0 + k0, Ad0);
        gll16(Ap1 + k0, Ad1);
        gll16(Bp0 + k0, Bd0);
        gll16(Bp1 + k0, Bd1);
        __syncthreads();
        short8 af[4], bf[4];
        #pragma unroll
        for (int i = 0; i < 4; ++i) af[i] = *(const short8*)&As[(wm + i*16 + fr)*32 + fk];
        #pragma unroll
        for (int j = 0; j < 4; ++j) bf[j] = *(const short8*)&Bs[(wn + j*16 + fr)*32 + fk];
        #pragma unroll
        for (int i = 0; i < 4; ++i)
            #pragma unroll
            for (int j = 0; j < 4; ++j)
                acc[i][j] = __builtin_amdgcn_mfma_f32_16x16x32_bf16(bf[j], af[i], acc[i][j], 0, 0, 0);
        __syncthreads();
    }
    // loop ends with a barrier: safe to alias smem for the out-tile.

    // ---- stage 1: pack fp16 into LDS out-tile [128][136] ----
    const int LD = 136;
    int en = lane & 15;
    int ev = (lane >> 4) * 4;
    #pragma unroll
    for (int i = 0; i < 4; ++i){
        int r = wm + i*16 + en;
        #pragma unroll
        for (int j = 0; j < 4; ++j){
            ushort4 h;
            h.x = f2h(acc[i][j][0]);
            h.y = f2h(acc[i][j][1]);
            h.z = f2h(acc[i][j][2]);
            h.w = f2h(acc[i][j][3]);
            *(ushort4*)&smem[r*LD + wn + j*16 + ev] = h;
        }
    }
    __syncthreads();

    // ---- stage 2: coalesced stores, 16 lanes cover one row's 256B ----
    int rr = tid >> 4;          // 0..15
    int cc = (tid & 15) * 8;    // element col, 16B per lane
    #pragma unroll
    for (int it = 0; it < 8; ++it){
        int r = it*16 + rr;
        int n = row0 + r;
        if (n < row_hi){
            u16x8 v = *(const u16x8*)&smem[r*LD + cc];
            *(u16x8*)&doth[(size_t)(n - row_lo) * V_ + col0 + cc] = v;
        }
    }
}

// ---------------- selection v6: 2 rows/wave for ILP on the serial chains ----------------
// Same math as the r5-proven v4, but each wave processes TWO rows with fully
// interleaved instruction streams: reconstruct+min/argmin/max fused in one pass,
// both rows' shfl reductions / scan / ballot bit-search / softmax interleave.
// The in-bin rank search is a fixed 32-iteration greedy from P=0 (same result:
// t = rank-rk value of the collected bin; shared high bits are adopted greedily).
__global__ __launch_bounds__(256, 2) void select_kernel(const unsigned short* __restrict__ doth,
                                                        const int* __restrict__ codes,
                                                        const float* __restrict__ esq,
                                                        const float* __restrict__ csq,
                                                        float2* __restrict__ pairbuf,
                                                        int row_lo, int nrows){
    int tid = threadIdx.x, lane = tid & 63, wv = tid >> 6;
    int lbase = blockIdx.x * 8 + wv * 2;
    if (lbase >= nrows) return;               // wave-uniform
    bool has1 = (lbase + 1 < nrows);
    int l0 = lbase, l1 = has1 ? lbase + 1 : lbase;
    int n0 = row_lo + l0, n1 = row_lo + l1;
    const u16x8* ra = (const u16x8*)(doth + (size_t)l0 * V_);
    const u16x8* rb = (const u16x8*)(doth + (size_t)l1 * V_);

    __shared__ unsigned hist[8][256] __attribute__((aligned(16)));
    __shared__ unsigned coll[8][64];
    __shared__ unsigned collcnt[8];
    int h0 = wv*2, h1 = wv*2 + 1;

    float es0 = esq[n0], es1 = esq[n1];
    int cd0 = codes[n0], cd1 = codes[n1];
    float dc0 = h2f(doth[(size_t)l0 * V_ + cd0]);
    float dc1 = h2f(doth[(size_t)l1 * V_ + cd1]);
    unsigned uc0 = __float_as_uint(fmaxf(es0 + csq[cd0] - 2.f * dc0, 0.f));
    unsigned uc1 = __float_as_uint(fmaxf(es1 + csq[cd1] - 2.f * dc1, 0.f));

    // ---- reconstruct + fused min/argmin/max (one pass, both rows) ----
    unsigned u0[64], u1[64];
    unsigned mn0 = 0xFFFFFFFFu, mx0 = 0u, mn1 = 0xFFFFFFFFu, mx1 = 0u;
    int km0 = 0, km1 = 0;
    #pragma unroll
    for (int j = 0; j < 8; ++j){
        u16x8 ha = ra[lane + j*64];
        u16x8 hb = rb[lane + j*64];
        const float4* cp = (const float4*)(csq + 8*lane + 512*j);
        float4 c0 = cp[0], c1 = cp[1];
        float cs[8] = {c0.x, c0.y, c0.z, c0.w, c1.x, c1.y, c1.z, c1.w};
        #pragma unroll
        for (int e = 0; e < 8; ++e){
            int k = 8*j + e;
            unsigned v0 = __float_as_uint(fmaxf(es0 + cs[e] - 2.f * h2f(ha[e]), 0.f));
            unsigned v1 = __float_as_uint(fmaxf(es1 + cs[e] - 2.f * h2f(hb[e]), 0.f));
            u0[k] = v0; u1[k] = v1;
            if (v0 < mn0){ mn0 = v0; km0 = k; }
            mx0 = (v0 > mx0) ? v0 : mx0;
            if (v1 < mn1){ mn1 = v1; km1 = k; }
            mx1 = (v1 > mx1) ? v1 : mx1;
        }
    }
    // per-lane min index -> global (val, idx) lexicographic reduce, both rows
    unsigned im0 = 8u*(unsigned)lane + (unsigned)(512*(km0 >> 3) + (km0 & 7));
    unsigned im1 = 8u*(unsigned)lane + (unsigned)(512*(km1 >> 3) + (km1 & 7));
    #pragma unroll
    for (int o = 32; o; o >>= 1){
        unsigned v2 = (unsigned)__shfl_xor((int)mn0, o, 64);
        unsigned i2 = (unsigned)__shfl_xor((int)im0, o, 64);
        if (v2 < mn0 || (v2 == mn0 && i2 < im0)){ mn0 = v2; im0 = i2; }
        unsigned x2 = (unsigned)__shfl_xor((int)mx0, o, 64); if (x2 > mx0) mx0 = x2;
        unsigned v3 = (unsigned)__shfl_xor((int)mn1, o, 64);
        unsigned i3 = (unsigned)__shfl_xor((int)im1, o, 64);
        if (v3 < mn1 || (v3 == mn1 && i3 < im1)){ mn1 = v3; im1 = i3; }
        unsigned x3 = (unsigned)__shfl_xor((int)mx1, o, 64); if (x3 > mx1) mx1 = x3;
    }
    int idx00 = (int)im0, idx01 = (int)im1;
    float d00 = sqrtf(__uint_as_float(mn0));
    float d01 = sqrtf(__uint_as_float(mn1));

    // ---- histograms (both rows; degenerate rows take the rare fallback) ----
    ((uint4*)&hist[h0][0])[lane] = (uint4){0u,0u,0u,0u};
    ((uint4*)&hist[h1][0])[lane] = (uint4){0u,0u,0u,0u};
    if (lane == 0){ collcnt[h0] = 0u; collcnt[h1] = 0u; }
    asm volatile("s_waitcnt lgkmcnt(0)" ::: "memory");
    float fmn0 = __uint_as_float(mn0), fmx0 = __uint_as_float(mx0);
    float fmn1 = __uint_as_float(mn1), fmx1 = __uint_as_float(mx1);
    float iw0 = (mx0 > mn0) ? 256.0f / (fmx0 - fmn0) : 0.f;
    float iw1 = (mx1 > mn1) ? 256.0f / (fmx1 - fmn1) : 0.f;
    float nb0 = -fmn0 * iw0, nb1 = -fmn1 * iw1;
    #pragma unroll
    for (int k = 0; k < 64; ++k){
        int b0 = (int)fmaf(__uint_as_float(u0[k]), iw0, nb0); b0 = (b0 > 255) ? 255 : b0;
        int b1 = (int)fmaf(__uint_as_float(u1[k]), iw1, nb1); b1 = (b1 > 255) ? 255 : b1;
        atomicAdd(&hist[h0][b0], 1u);
        atomicAdd(&hist[h1][b1], 1u);
    }
    asm volatile("s_waitcnt lgkmcnt(0)" ::: "memory");

    // ---- exclusive scan over 256 bins (4/lane), find rank-99 bin, both rows ----
    uint4 hq0 = ((uint4*)&hist[h0][0])[lane];
    uint4 hq1 = ((uint4*)&hist[h1][0])[lane];
    unsigned ls0 = hq0.x + hq0.y + hq0.z + hq0.w;
    unsigned ls1 = hq1.x + hq1.y + hq1.z + hq1.w;
    unsigned in0 = ls0, in1 = ls1;
    #pragma unroll
    for (int o = 1; o < 64; o <<= 1){
        unsigned y0 = (unsigned)__shfl_up((int)in0, o, 64);
        unsigned y1 = (unsigned)__shfl_up((int)in1, o, 64);
        if (lane >= o){ in0 += y0; in1 += y1; }
    }
    unsigned e00 = in0 - ls0;
    unsigned e01 = e00 + hq0.x, e02 = e01 + hq0.y, e03 = e02 + hq0.z, e04 = e03 + hq0.w;
    int s0 = -1;
    if      (e00 <= 99u && 99u < e01) s0 = 0;
    else if (e01 <= 99u && 99u < e02) s0 = 1;
    else if (e02 <= 99u && 99u < e03) s0 = 2;
    else if (e03 <= 99u && 99u < e04) s0 = 3;
    unsigned e10 = in1 - ls1;
    unsigned e11 = e10 + hq1.x, e12 = e11 + hq1.y, e13 = e12 + hq1.z, e14 = e13 + hq1.w;
    int s1 = -1;
    if      (e10 <= 99u && 99u < e11) s1 = 0;
    else if (e11 <= 99u && 99u < e12) s1 = 1;
    else if (e12 <= 99u && 99u < e13) s1 = 2;
    else if (e13 <= 99u && 99u < e14) s1 = 3;
    u64 bl0 = __ballot(s0 >= 0);
    u64 bl1 = __ballot(s1 >= 0);
    int sr0 = __ffsll(bl0) - 1;
    int sr1 = __ffsll(bl1) - 1;
    unsigned mB0 = (unsigned)(4*lane + (s0 < 0 ? 0 : s0));
    unsigned mB1 = (unsigned)(4*lane + (s1 < 0 ? 0 : s1));
    unsigned mE0 = (s0 == 1) ? e01 : (s0 == 2) ? e02 : (s0 == 3) ? e03 : e00;
    unsigned mE1 = (s1 == 1) ? e11 : (s1 == 2) ? e12 : (s1 == 3) ? e13 : e10;
    int Bk0 = __shfl((int)mB0, sr0, 64);
    int Bk1 = __shfl((int)mB1, sr1, 64);
    int ba0 = __shfl((int)mE0, sr0, 64);
    int ba1 = __shfl((int)mE1, sr1, 64);
    int rk0 = 99 - ba0, rk1 = 99 - ba1;

    // ---- collect rank bin values (both rows) ----
    #pragma unroll
    for (int k = 0; k < 64; ++k){
        int b0 = (int)fmaf(__uint_as_float(u0[k]), iw0, nb0); b0 = (b0 > 255) ? 255 : b0;
        int b1 = (int)fmaf(__uint_as_float(u1[k]), iw1, nb1); b1 = (b1 > 255) ? 255 : b1;
        if (b0 == Bk0){
            unsigned pos = atomicAdd(&collcnt[h0], 1u);
            if (pos < 64u) coll[h0][pos] = u0[k];
        }
        if (b1 == Bk1){
            unsigned pos = atomicAdd(&collcnt[h1], 1u);
            if (pos < 64u) coll[h1][pos] = u1[k];
        }
    }
    asm volatile("s_waitcnt lgkmcnt(0)" ::: "memory");
    int bc0 = (int)collcnt[h0], bc1 = (int)collcnt[h1];

    // ---- rank-rk within bin: fixed-32 greedy from P=0 (interleaved) ----
    unsigned t0u, t1u;
    bool f0 = bc0 > 64, f1 = bc1 > 64;
    unsigned w0 = 0xFFFFFFFFu, w1 = 0xFFFFFFFFu;
    if (!f0) w0 = (lane < bc0) ? coll[h0][lane] : 0xFFFFFFFFu;
    if (!f1) w1 = (lane < bc1) ? coll[h1][lane] : 0xFFFFFFFFu;
    if (!f0 && !f1){
        unsigned P0 = 0u, P1 = 0u;
        #pragma unroll
        for (int b = 31; b >= 0; --b){
            unsigned c0 = P0 | (1u << b);
            unsigned c1 = P1 | (1u << b);
            int q0 = (int)__popcll(__ballot(w0 < c0));
            int q1 = (int)__popcll(__ballot(w1 < c1));
            if (q0 <= rk0) P0 = c0;
            if (q1 <= rk1) P1 = c1;
        }
        t0u = P0; t1u = P1;
    } else {
        // rare: at least one overfull bin -> per-row handling
        if (!f0){
            unsigned P = 0u;
            #pragma unroll
            for (int b = 31; b >= 0; --b){
                unsigned c = P | (1u << b);
                if ((int)__popcll(__ballot(w0 < c)) <= rk0) P = c;
            }
            t0u = P;
        } else {
            unsigned P = 0u;
            for (int b = 31; b >= 0; --b){
                unsigned cand = P | (1u << b);
                int c = 0;
                #pragma unroll
                for (int k = 0; k < 64; ++k) c += (u0[k] < cand) ? 1 : 0;
                #pragma unroll
                for (int o = 32; o; o >>= 1) c += __shfl_xor(c, o, 64);
                if (c <= 99) P = cand;
            }
            t0u = P;
        }
        if (!f1){
            unsigned P = 0u;
            #pragma unroll
            for (int b = 31; b >= 0; --b){
                unsigned c = P | (1u << b);
                if ((int)__popcll(__ballot(w1 < c)) <= rk1) P = c;
            }
            t1u = P;
        } else {
            unsigned P = 0u;
            for (int b = 31; b >= 0; --b){
                unsigned cand = P | (1u << b);
                int c = 0;
                #pragma unroll
                for (int k = 0; k < 64; ++k) c += (u1[k] < cand) ? 1 : 0;
                #pragma unroll
                for (int o = 32; o; o >>= 1) c += __shfl_xor(c, o, 64);
                if (c <= 99) P = cand;
            }
            t1u = P;
        }
    }
    float tv0 = sqrtf(__uint_as_float(t0u));
    float tv1 = sqrtf(__uint_as_float(t1u));

    // ---- softmax denom over top-100 (both rows interleaved) ----
    float sm0 = 0.f, sm1 = 0.f;
    int cl0 = 0, cl1 = 0;
    #pragma unroll
    for (int k = 0; k < 64; ++k){
        if (u0[k] < t0u){ sm0 += __expf(d00 - sqrtf(__uint_as_float(u0[k]))); cl0++; }
        if (u1[k] < t1u){ sm1 += __expf(d01 - sqrtf(__uint_as_float(u1[k]))); cl1++; }
    }
    #pragma unroll
    for (int o = 32; o; o >>= 1){
        sm0 += __shfl_xor(sm0, o, 64); cl0 += __shfl_xor(cl0, o, 64);
        sm1 += __shfl_xor(sm1, o, 64); cl1 += __shfl_xor(cl1, o, 64);
    }
    if (lane == 0){
        {
            float S = sm0 + (float)(K_ - cl0) * __expf(d00 - tv0);
            float dcode = sqrtf(__uint_as_float(uc0));
            if (uc0 > t0u) S += __expf(d00 - dcode) - __expf(d00 - tv0);
            float nll = dcode - d00 + __logf(S);
            pairbuf[n0] = make_float2(nll, (idx00 == cd0) ? 1.f : 0.f);
        }
        if (has1){
            float S = sm1 + (float)(K_ - cl1) * __expf(d01 - tv1);
            float dcode = sqrtf(__uint_as_float(uc1));
            if (uc1 > t1u) S += __expf(d01 - dcode) - __expf(d01 - tv1);
            float nll = dcode - d01 + __logf(S);
            pairbuf[n1] = make_float2(nll, (idx01 == cd1) ? 1.f : 0.f);
        }
    }
}

__global__ __launch_bounds__(1024) void finalize_kernel(const float2* __restrict__ pair,
                                                        float* __restrict__ out){
    int tid = threadIdx.x;
    float sn = 0.f, sh = 0.f;
    for (int i = tid; i < N_; i += 1024){
        float2 p = pair[i]; sn += p.x; sh += p.y;
    }
    #pragma unroll
    for (int o = 32; o; o >>= 1){ sn += __shfl_down(sn, o, 64); sh += __shfl_down(sh, o, 64); }
    __shared__ float a[16], b[16];
    int wv = tid >> 6, lane = tid & 63;
    if (lane == 0){ a[wv] = sn; b[wv] = sh; }
    __syncthreads();
    if (tid == 0){
        float L = 0.f, H = 0.f;
        #pragma unroll
        for (int i = 0; i < 16; ++i){ L += a[i]; H += b[i]; }
        out[0] = L / (float)N_;
        out[1] = H / (float)N_;   // local prediction is always candidate 0
        out[2] = H / (float)N_;
        out[3] = 1.0f;            // include_correct guarantees membership
    }
}

// ---------------- launcher (gemm split 2, single full-N select) ----------------
extern "C" void kernel_launch(void* const* d_in, const int* in_sizes, int n_in,
                              void* d_out, int out_size, void* d_ws, size_t ws_size,
                              hipStream_t stream){
    const float* S   = (const float*)d_in[0];
    const int* codes = (const int*)d_in[1];
    const float* CB  = (const float*)d_in[2];
    float* out = (float*)d_out;

    char* w = (char*)d_ws;
    size_t off = 0;
    unsigned short* embT = (unsigned short*)(w + off); off += (size_t)NPAD_ * C_ * 2;
    unsigned short* CBh  = (unsigned short*)(w + off); off += (size_t)V_ * C_ * 2;
    float* csq = (float*)(w + off); off += (size_t)V_ * 4;
    float* esq = (float*)(w + off); off += (size_t)N_ * 4;
    off = (off + 255) & ~(size_t)255;
    float2* pairbuf = (float2*)(w + off); off += (size_t)N_ * 8;
    unsigned short* dotbuf = (unsigned short*)(w + off);

    size_t avail = (ws_size > off) ? ws_size - off : 0;
    long maxrows = (long)(avail / ((size_t)V_ * 2));

    hipMemsetAsync(esq, 0, (size_t)N_ * 4, stream);
    hipLaunchKernelGGL(cbconv_kernel, dim3(V_/4), dim3(256), 0, stream, CB, CBh, csq);
    hipLaunchKernelGGL(transpose_conv_kernel, dim3((T_+31)/32, C_/32, B_), dim3(32, 8), 0, stream,
                       S, embT, esq);

    if (maxrows >= N_){
        const int gchunk = 6144;   // multiple of 128
        for (int row_lo = 0; row_lo < N_; row_lo += gchunk){
            int row_hi = row_lo + gchunk; if (row_hi > N_) row_hi = N_;
            int rows = row_hi - row_lo;
            hipLaunchKernelGGL(gemm_dot_kernel, dim3((rows + 127)/128, V_/128), dim3(256), 0, stream,
                               embT, CBh, dotbuf + (size_t)row_lo * V_, row_lo, row_hi);
        }
        hipLaunchKernelGGL(select_kernel, dim3((N_ + 7)/8), dim3(256), 0, stream,
                           dotbuf, codes, esq, csq, pairbuf, 0, N_);
    } else {
        int chunk = (int)(maxrows & ~127L);
        if (chunk < 128) chunk = 128;
        for (int row_lo = 0; row_lo < N_; row_lo += chunk){
            int row_hi = row_lo + chunk; if (row_hi > N_) row_hi = N_;
            int rows = row_hi - row_lo;
            hipLaunchKernelGGL(gemm_dot_kernel, dim3((rows + 127)/128, V_/128), dim3(256), 0, stream,
                               embT, CBh, dotbuf, row_lo, row_hi);
            hipLaunchKernelGGL(select_kernel, dim3((rows + 7)/8), dim3(256), 0, stream,
                               dotbuf, codes, esq, csq, pairbuf, row_lo, rows);
        }
    }
    hipLaunchKernelGGL(finalize_kernel, dim3(1), dim3(1024), 0, stream, pairbuf, out);
}

// Round 9
// 215.928 us; speedup vs baseline: 1.2574x; 1.2574x over previous
//
#include <hip/hip_runtime.h>
#include <hip/hip_bf16.h>
#include <cstdint>

#define B_ 8
#define C_ 512
#define T_ 1500
#define N_ (B_*T_)      // 12000 tokens
#define NPAD_ 12032
#define V_ 4096
#define K_ 100

typedef unsigned long long u64;
typedef __attribute__((ext_vector_type(8))) short short8;
typedef __attribute__((ext_vector_type(8))) unsigned short u16x8;
typedef __attribute__((ext_vector_type(4))) float f32x4;

__device__ __forceinline__ unsigned short f2bf(float x){
    __hip_bfloat16 h = __float2bfloat16(x);
    return __builtin_bit_cast(unsigned short, h);
}
__device__ __forceinline__ unsigned short f2h(float x){
    return __builtin_bit_cast(unsigned short, (_Float16)x);
}
__device__ __forceinline__ float h2f(unsigned short h){
    return (float)__builtin_bit_cast(_Float16, h);
}

__device__ __forceinline__ void gll16(const unsigned short* g, unsigned short* l){
    __builtin_amdgcn_global_load_lds(
        (const __attribute__((address_space(1))) void*)g,
        (__attribute__((address_space(3))) void*)l, 16, 0, 0);
}

// ---------------- codebook: fp32 -> bf16 + csq (fp32-exact) ----------------
__global__ __launch_bounds__(256) void cbconv_kernel(const float* __restrict__ CB,
                                                     unsigned short* __restrict__ CBh,
                                                     float* __restrict__ csq){
    int wv = threadIdx.x >> 6, lane = threadIdx.x & 63;
    int r = blockIdx.x * 4 + wv;
    const float4* p4 = (const float4*)(CB + (size_t)r * C_);
    ushort4* o4 = (ushort4*)(CBh + (size_t)r * C_);
    float s = 0.f;
    #pragma unroll
    for (int j = 0; j < 2; ++j){
        float4 v = p4[lane + j*64];
        s += v.x*v.x + v.y*v.y + v.z*v.z + v.w*v.w;
        ushort4 h; h.x = f2bf(v.x); h.y = f2bf(v.y); h.z = f2bf(v.z); h.w = f2bf(v.w);
        o4[lane + j*64] = h;
    }
    #pragma unroll
    for (int o = 32; o; o >>= 1) s += __shfl_down(s, o, 64);
    if (lane == 0) csq[r] = s;
}

// ---------------- student: (B,C,T) fp32 -> embT bf16 (N,C) + esq partials ----------------
__global__ __launch_bounds__(256) void transpose_conv_kernel(const float* __restrict__ S,
                                                             unsigned short* __restrict__ embT,
                                                             float* __restrict__ esq){
    __shared__ float tile[32][33];
    __shared__ float psum[8][33];
    int b  = blockIdx.z;
    int c0 = blockIdx.y * 32;
    int t0 = blockIdx.x * 32;
    int tx = threadIdx.x, ty = threadIdx.y; // 32 x 8
    #pragma unroll
    for (int r = 0; r < 4; ++r){
        int c = c0 + ty + r*8;
        int t = t0 + tx;
        tile[ty + r*8][tx] = (t < T_) ? S[((size_t)b*C_ + c)*T_ + t] : 0.f;
    }
    __syncthreads();
    float ps = 0.f;
    #pragma unroll
    for (int r = 0; r < 4; ++r){ float v = tile[ty + r*8][tx]; ps += v * v; }
    psum[ty][tx] = ps;
    #pragma unroll
    for (int r = 0; r < 4; ++r){
        int t = t0 + ty + r*8;
        int c = c0 + tx;
        if (t < T_) embT[((size_t)b*T_ + t)*C_ + c] = f2bf(tile[tx][ty + r*8]);
    }
    __syncthreads();
    if (ty == 0){
        int t = t0 + tx;
        if (t < T_){
            float s2 = 0.f;
            #pragma unroll
            for (int w = 0; w < 8; ++w) s2 += psum[w][tx];
            atomicAdd(&esq[b*T_ + t], s2);
        }
    }
}

// ---------------- bf16 MFMA GEMM -> fp16 dot matrix (r2-proven 2-barrier 128^2) ----------------
__global__ __launch_bounds__(256) void gemm_dot_kernel(
    const unsigned short* __restrict__ A, const unsigned short* __restrict__ Bm,
    unsigned short* __restrict__ doth, int row_lo, int row_hi)
{
    __shared__ unsigned short smem[128*136];   // 34816 B; staging (16 KB) aliased in front
    unsigned short* As = smem;                 // 128*32
    unsigned short* Bs = smem + 128*32;        // 128*32
    int tid = threadIdx.x, lane = tid & 63, wv = tid >> 6;
    int row0 = row_lo + blockIdx.x * 128;
    int col0 = blockIdx.y * 128;

    int sr = lane >> 2;
    int sk = (lane & 3) * 8;
    int ar0 = row0 + wv*32 + sr;       int ar1 = ar0 + 16;
    int ca0 = (ar0 < N_) ? ar0 : N_-1; int ca1 = (ar1 < N_) ? ar1 : N_-1;
    const unsigned short* Ap0 = A  + (size_t)ca0 * C_ + sk;
    const unsigned short* Ap1 = A  + (size_t)ca1 * C_ + sk;
    const unsigned short* Bp0 = Bm + (size_t)(col0 + wv*32 + sr) * C_ + sk;
    const unsigned short* Bp1 = Bp0 + (size_t)16 * C_;
    unsigned short* Ad0 = &As[(wv*32     ) * 32];
    unsigned short* Ad1 = &As[(wv*32 + 16) * 32];
    unsigned short* Bd0 = &Bs[(wv*32     ) * 32];
    unsigned short* Bd1 = &Bs[(wv*32 + 16) * 32];

    int wm = (wv >> 1) * 64, wn = (wv & 1) * 64;
    int fr = lane & 15;
    int fk = (lane >> 4) * 8;

    f32x4 acc[4][4];
    #pragma unroll
    for (int i = 0; i < 4; ++i)
        #pragma unroll
        for (int j = 0; j < 4; ++j) acc[i][j] = (f32x4){0.f, 0.f, 0.f, 0.f};

    for (int kt = 0; kt < C_/32; ++kt){
        int k0 = kt * 32;
        gll16(Ap0 + k0, Ad0);
        gll16(Ap1 + k0, Ad1);
        gll16(Bp0 + k0, Bd0);
        gll16(Bp1 + k0, Bd1);
        __syncthreads();
        short8 af[4], bf[4];
        #pragma unroll
        for (int i = 0; i < 4; ++i) af[i] = *(const short8*)&As[(wm + i*16 + fr)*32 + fk];
        #pragma unroll
        for (int j = 0; j < 4; ++j) bf[j] = *(const short8*)&Bs[(wn + j*16 + fr)*32 + fk];
        #pragma unroll
        for (int i = 0; i < 4; ++i)
            #pragma unroll
            for (int j = 0; j < 4; ++j)
                acc[i][j] = __builtin_amdgcn_mfma_f32_16x16x32_bf16(bf[j], af[i], acc[i][j], 0, 0, 0);
        __syncthreads();
    }
    // loop ends with a barrier: safe to alias smem for the out-tile.

    // ---- stage 1: pack fp16 into LDS out-tile [128][136] ----
    const int LD = 136;
    int en = lane & 15;
    int ev = (lane >> 4) * 4;
    #pragma unroll
    for (int i = 0; i < 4; ++i){
        int r = wm + i*16 + en;
        #pragma unroll
        for (int j = 0; j < 4; ++j){
            ushort4 h;
            h.x = f2h(acc[i][j][0]);
            h.y = f2h(acc[i][j][1]);
            h.z = f2h(acc[i][j][2]);
            h.w = f2h(acc[i][j][3]);
            *(ushort4*)&smem[r*LD + wn + j*16 + ev] = h;
        }
    }
    __syncthreads();

    // ---- stage 2: coalesced stores, 16 lanes cover one row's 256B ----
    int rr = tid >> 4;          // 0..15
    int cc = (tid & 15) * 8;    // element col, 16B per lane
    #pragma unroll
    for (int it = 0; it < 8; ++it){
        int r = it*16 + rr;
        int n = row0 + r;
        if (n < row_hi){
            u16x8 v = *(const u16x8*)&smem[r*LD + cc];
            *(u16x8*)&doth[(size_t)(n - row_lo) * V_ + col0 + cc] = v;
        }
    }
}

// ---------------- selection v4.1: r5-proven structure, argmin fused into reconstruct ----------------
__global__ __launch_bounds__(256, 2) void select_kernel(const unsigned short* __restrict__ doth,
                                                        const int* __restrict__ codes,
                                                        const float* __restrict__ esq,
                                                        const float* __restrict__ csq,
                                                        float2* __restrict__ pairbuf,
                                                        int row_lo, int nrows){
    int tid = threadIdx.x, lane = tid & 63, wv = tid >> 6;
    int lrow = blockIdx.x * 4 + wv;
    if (lrow >= nrows) return;               // wave-uniform, no barriers below
    int n = row_lo + lrow;
    const u16x8* r8 = (const u16x8*)(doth + (size_t)lrow * V_);

    __shared__ unsigned hist[4][256] __attribute__((aligned(16)));
    __shared__ unsigned coll[4][64];
    __shared__ unsigned collcnt[4];

    float esq_n = esq[n];
    int code = codes[n];
    float dotc = h2f(doth[(size_t)lrow * V_ + code]);
    unsigned ucode = __float_as_uint(fmaxf(esq_n + csq[code] - 2.f * dotc, 0.f));

    // ---- load + reconstruct d2 bits, with fused per-lane min/argmin/max ----
    // (fused tracking verified correct in r6/r8: per-lane first-k strict-< min has
    //  the lane's lowest global idx since idx=512j+8lane+e increases with k)
    unsigned u[64];
    unsigned vmn = 0xFFFFFFFFu, vmx = 0u;
    int km = 0;
    #pragma unroll
    for (int j = 0; j < 8; ++j){
        u16x8 h = r8[lane + j*64];
        const float4* cp = (const float4*)(csq + 8*lane + 512*j);
        float4 c0 = cp[0], c1 = cp[1];
        float cs[8] = {c0.x, c0.y, c0.z, c0.w, c1.x, c1.y, c1.z, c1.w};
        #pragma unroll
        for (int e = 0; e < 8; ++e){
            int k = 8*j + e;
            unsigned v = __float_as_uint(fmaxf(esq_n + cs[e] - 2.f * h2f(h[e]), 0.f));
            u[k] = v;
            if (v < vmn){ vmn = v; km = k; }
            vmx = (v > vmx) ? v : vmx;
        }
    }
    // joint (val, idx) lexicographic reduce + max reduce
    unsigned im = 8u*(unsigned)lane + (unsigned)(512*(km >> 3) + (km & 7));
    #pragma unroll
    for (int o = 32; o; o >>= 1){
        unsigned v2 = (unsigned)__shfl_xor((int)vmn, o, 64);
        unsigned i2 = (unsigned)__shfl_xor((int)im,  o, 64);
        if (v2 < vmn || (v2 == vmn && i2 < im)){ vmn = v2; im = i2; }
        unsigned x2 = (unsigned)__shfl_xor((int)vmx, o, 64); if (x2 > vmx) vmx = x2;
    }
    unsigned umin = vmn, umax = vmx;
    int idx0 = (int)im;
    float d0 = sqrtf(__uint_as_float(umin));

    // ---- rank-99 threshold t via per-wave histogram + in-bin bitwise search ----
    unsigned t;
    if (umin == umax){
        t = umin;
    } else {
        ((uint4*)&hist[wv][0])[lane] = (uint4){0u,0u,0u,0u};
        if (lane == 0) collcnt[wv] = 0u;
        asm volatile("s_waitcnt lgkmcnt(0)" ::: "memory");
        float fmn = __uint_as_float(umin), fmx = __uint_as_float(umax);
        float invw = 256.0f / (fmx - fmn);
        #pragma unroll
        for (int k = 0; k < 64; ++k){
            float fk = __uint_as_float(u[k]);
            int b = (int)((fk - fmn) * invw); b = (b > 255) ? 255 : b;
            atomicAdd(&hist[wv][b], 1u);
        }
        asm volatile("s_waitcnt lgkmcnt(0)" ::: "memory");
        uint4 hq = ((uint4*)&hist[wv][0])[lane];
        unsigned lsum = hq.x + hq.y + hq.z + hq.w;
        unsigned inc = lsum;
        #pragma unroll
        for (int o = 1; o < 64; o <<= 1){
            unsigned y = (unsigned)__shfl_up((int)inc, o, 64);
            if (lane >= o) inc += y;
        }
        unsigned e0 = inc - lsum;
        unsigned e1 = e0 + hq.x, e2 = e1 + hq.y, e3 = e2 + hq.z, e4 = e3 + hq.w;
        int sel = -1;
        if      (e0 <= 99u && 99u < e1) sel = 0;
        else if (e1 <= 99u && 99u < e2) sel = 1;
        else if (e2 <= 99u && 99u < e3) sel = 2;
        else if (e3 <= 99u && 99u < e4) sel = 3;
        u64 bal = __ballot(sel >= 0);
        int src = __ffsll(bal) - 1;
        unsigned myBk = (unsigned)(4*lane + (sel < 0 ? 0 : sel));
        unsigned myBase = (sel == 1) ? e1 : (sel == 2) ? e2 : (sel == 3) ? e3 : e0;
        int Bk   = __shfl((int)myBk,   src, 64);
        int base = __shfl((int)myBase, src, 64);
        int rk = 99 - base;
        #pragma unroll
        for (int k = 0; k < 64; ++k){
            float fk = __uint_as_float(u[k]);
            int b = (int)((fk - fmn) * invw); b = (b > 255) ? 255 : b;
            if (b == Bk){
                unsigned pos = atomicAdd(&collcnt[wv], 1u);
                if (pos < 64u) coll[wv][pos] = u[k];
            }
        }
        asm volatile("s_waitcnt lgkmcnt(0)" ::: "memory");
        unsigned bcnt = collcnt[wv];
        if (bcnt <= 64u){
            unsigned w = (lane < (int)bcnt) ? coll[wv][lane] : 0xFFFFFFFFu;
            unsigned wmn = (lane < (int)bcnt) ? w : 0xFFFFFFFFu;
            unsigned wmx = (lane < (int)bcnt) ? w : 0u;
            #pragma unroll
            for (int o = 32; o; o >>= 1){
                unsigned a = (unsigned)__shfl_xor((int)wmn, o, 64); if (a < wmn) wmn = a;
                unsigned b = (unsigned)__shfl_xor((int)wmx, o, 64); if (b > wmx) wmx = b;
            }
            unsigned P;
            if (wmn == wmx) P = wmn;
            else {
                int hb = 31 - __clz((int)(wmn ^ wmx));
                unsigned mask = (hb == 31) ? 0xFFFFFFFFu : ((1u << (hb+1)) - 1u);
                P = wmn & ~mask;
                for (int b = hb; b >= 0; --b){
                    unsigned cand = P | (1u << b);
                    int c = __popcll(__ballot(w < cand));
                    if (c <= rk) P = cand;
                }
            }
            t = P;
        } else {
            int hb = 31 - __clz((int)(umin ^ umax));
            unsigned mask = (hb == 31) ? 0xFFFFFFFFu : ((1u << (hb+1)) - 1u);
            unsigned P = umin & ~mask;
            for (int b = hb; b >= 0; --b){
                unsigned cand = P | (1u << b);
                int c = 0;
                #pragma unroll
                for (int k = 0; k < 64; ++k) c += (u[k] < cand) ? 1 : 0;
                #pragma unroll
                for (int o = 32; o; o >>= 1) c += __shfl_xor(c, o, 64);
                if (c <= 99) P = cand;
            }
            t = P;
        }
    }
    float tval = sqrtf(__uint_as_float(t));

    // ---- softmax denom over top-100 (tie multiplicity at t) ----
    float s = 0.f; int cl = 0;
    #pragma unroll
    for (int k = 0; k < 64; ++k){
        if (u[k] < t){ s += __expf(d0 - sqrtf(__uint_as_float(u[k]))); cl++; }
    }
    #pragma unroll
    for (int o = 32; o; o >>= 1){
        s += __shfl_xor(s, o, 64);
        cl += __shfl_xor(cl, o, 64);
    }
    if (lane == 0){
        float S = s + (float)(K_ - cl) * __expf(d0 - tval);
        float dcode = sqrtf(__uint_as_float(ucode));
        if (ucode > t) S += __expf(d0 - dcode) - __expf(d0 - tval);  // include_correct swap
        float nll = dcode - d0 + __logf(S);
        pairbuf[n] = make_float2(nll, (idx0 == code) ? 1.f : 0.f);
    }
}

__global__ __launch_bounds__(1024) void finalize_kernel(const float2* __restrict__ pair,
                                                        float* __restrict__ out){
    int tid = threadIdx.x;
    float sn = 0.f, sh = 0.f;
    for (int i = tid; i < N_; i += 1024){
        float2 p = pair[i]; sn += p.x; sh += p.y;
    }
    #pragma unroll
    for (int o = 32; o; o >>= 1){ sn += __shfl_down(sn, o, 64); sh += __shfl_down(sh, o, 64); }
    __shared__ float a[16], b[16];
    int wv = tid >> 6, lane = tid & 63;
    if (lane == 0){ a[wv] = sn; b[wv] = sh; }
    __syncthreads();
    if (tid == 0){
        float L = 0.f, H = 0.f;
        #pragma unroll
        for (int i = 0; i < 16; ++i){ L += a[i]; H += b[i]; }
        out[0] = L / (float)N_;
        out[1] = H / (float)N_;   // local prediction is always candidate 0
        out[2] = H / (float)N_;
        out[3] = 1.0f;            // include_correct guarantees membership
    }
}

// ---------------- launcher (r6/r7-proven: gemm split 2, single full-N select) ----------------
extern "C" void kernel_launch(void* const* d_in, const int* in_sizes, int n_in,
                              void* d_out, int out_size, void* d_ws, size_t ws_size,
                              hipStream_t stream){
    const float* S   = (const float*)d_in[0];
    const int* codes = (const int*)d_in[1];
    const float* CB  = (const float*)d_in[2];
    float* out = (float*)d_out;

    char* w = (char*)d_ws;
    size_t off = 0;
    unsigned short* embT = (unsigned short*)(w + off); off += (size_t)NPAD_ * C_ * 2;
    unsigned short* CBh  = (unsigned short*)(w + off); off += (size_t)V_ * C_ * 2;
    float* csq = (float*)(w + off); off += (size_t)V_ * 4;
    float* esq = (float*)(w + off); off += (size_t)N_ * 4;
    off = (off + 255) & ~(size_t)255;
    float2* pairbuf = (float2*)(w + off); off += (size_t)N_ * 8;
    unsigned short* dotbuf = (unsigned short*)(w + off);

    size_t avail = (ws_size > off) ? ws_size - off : 0;
    long maxrows = (long)(avail / ((size_t)V_ * 2));

    hipMemsetAsync(esq, 0, (size_t)N_ * 4, stream);
    hipLaunchKernelGGL(cbconv_kernel, dim3(V_/4), dim3(256), 0, stream, CB, CBh, csq);
    hipLaunchKernelGGL(transpose_conv_kernel, dim3((T_+31)/32, C_/32, B_), dim3(32, 8), 0, stream,
                       S, embT, esq);

    if (maxrows >= N_){
        const int gchunk = 6144;   // multiple of 128
        for (int row_lo = 0; row_lo < N_; row_lo += gchunk){
            int row_hi = row_lo + gchunk; if (row_hi > N_) row_hi = N_;
            int rows = row_hi - row_lo;
            hipLaunchKernelGGL(gemm_dot_kernel, dim3((rows + 127)/128, V_/128), dim3(256), 0, stream,
                               embT, CBh, dotbuf + (size_t)row_lo * V_, row_lo, row_hi);
        }
        hipLaunchKernelGGL(select_kernel, dim3((N_ + 3)/4), dim3(256), 0, stream,
                           dotbuf, codes, esq, csq, pairbuf, 0, N_);
    } else {
        int chunk = (int)(maxrows & ~127L);
        if (chunk < 128) chunk = 128;
        for (int row_lo = 0; row_lo < N_; row_lo += chunk){
            int row_hi = row_lo + chunk; if (row_hi > N_) row_hi = N_;
            int rows = row_hi - row_lo;
            hipLaunchKernelGGL(gemm_dot_kernel, dim3((rows + 127)/128, V_/128), dim3(256), 0, stream,
                               embT, CBh, dotbuf, row_lo, row_hi);
            hipLaunchKernelGGL(select_kernel, dim3((rows + 3)/4), dim3(256), 0, stream,
                               dotbuf, codes, esq, csq, pairbuf, row_lo, rows);
        }
    }
    hipLaunchKernelGGL(finalize_kernel, dim3(1), dim3(1024), 0, stream, pairbuf, out);
}